// Round 12
// baseline (90.971 us; speedup 1.0000x reference)
//
#include <hip/hip_runtime.h>
#include <hip/hip_bf16.h>

typedef __bf16 bf16x8 __attribute__((ext_vector_type(8)));
typedef float  f32x4  __attribute__((ext_vector_type(4)));

#define IN_F   4096
#define OUT_F  4096
#define RANK   32

__device__ __forceinline__ bf16x8 cvt8(float4 a, float4 b) {
    bf16x8 r;
    r[0] = (__bf16)a.x; r[1] = (__bf16)a.y; r[2] = (__bf16)a.z; r[3] = (__bf16)a.w;
    r[4] = (__bf16)b.x; r[5] = (__bf16)b.y; r[6] = (__bf16)b.z; r[7] = (__bf16)b.w;
    return r;
}

__device__ __forceinline__ void gl_lds16(const float* g, void* l) {
    __builtin_amdgcn_global_load_lds(
        (const __attribute__((address_space(1))) char*)g,
        (__attribute__((address_space(3))) char*)l, 16, 0, 0);
}

// ---------------- Kernel 1: Hpart[ks] = (X @ V^T) * S over k-slice ----------------
// grid (256, KS), 256 thr (4 waves). Block: 32 tokens x (IN_F/KS) feats in
// 256-feat chunks -> each X row read in 1 KB contiguous bursts (DRAM page
// locality; was 256 B). X-only LDS double buffer (64 KB, 2 blocks/CU);
// V fragments come from L2 into registers (issued early, vmcnt-counted).
// Wave = (tt = token 16-tile, rh = rank half); acc = 16 tok x 16 ranks.
template <int KS>
__global__ __launch_bounds__(256, 2)
void lora_h(const float* __restrict__ X, const float* __restrict__ S,
            const float* __restrict__ V, float* __restrict__ Hpart)
{
    constexpr int F    = IN_F / KS;
    constexpr int NCHK = F / 256;

    __shared__ float4 XB[2][2][8][2][64];   // [buf][tt][s][h][slot] 64 KB

    const int tid  = threadIdx.x;
    const int wave = tid >> 6;
    const int lane = tid & 63;
    const int r    = lane & 15;
    const int kg   = lane >> 4;

    const int tt = wave & 1;                // token 16-tile this wave computes
    const int rh = wave >> 1;               // rank half this wave computes

    const int t0    = blockIdx.x * 32;
    const int fbase = blockIdx.y * F;

    // stage chunk c into buffer nb: 32 x 1KB instructions, 8 per wave.
    // Per-wave issue order walks (s,h) lexicographic -> each of its 16 rows
    // advances in consecutive 64 B steps (1 KB sequential per row per chunk).
    auto stage = [&](int c, int nb) {
        const int fc = fbase + ((c + blockIdx.x) & (NCHK - 1)) * 256;
        #pragma unroll
        for (int t = 0; t < 8; ++t) {
            const int inst = wave * 8 + t;
            const int ti = inst >> 4, s = (inst >> 1) & 7, h2 = inst & 1;
            gl_lds16(X + (size_t)(t0 + ti * 16 + r) * IN_F
                       + fc + s * 32 + h2 * 16 + kg * 4,
                     (void*)&XB[nb][ti][s][h2][0]);
        }
    };

    // V fragments for chunk c -> registers (L2-hot after first blocks).
    // B-frag: lane (r,kg) needs V[rh*16+r][fc + s*32 + kg*8 .. +8].
    float4 vv[16];
    auto vload = [&](int c) {
        const int fc = fbase + ((c + blockIdx.x) & (NCHK - 1)) * 256;
        const float* vrow = V + (size_t)(rh * 16 + r) * IN_F + fc + kg * 8;
        #pragma unroll
        for (int s = 0; s < 8; ++s) {
            const float4* vp = reinterpret_cast<const float4*>(vrow + s * 32);
            vv[2 * s]     = vp[0];
            vv[2 * s + 1] = vp[1];
        }
    };

    const int h  = kg >> 1;
    const int qb = (kg & 1) * 2;

    f32x4 acc = {0.f, 0.f, 0.f, 0.f};

    auto compute = [&](int cur) {
        #pragma unroll
        for (int s = 0; s < 8; ++s) {
            float4 x0 = *(const float4*)&XB[cur][tt][s][h][qb * 16 + r];
            float4 x1 = *(const float4*)&XB[cur][tt][s][h][(qb + 1) * 16 + r];
            // A = X (m = token), B = V (n = rank-in-half), K = 32 feats
            acc = __builtin_amdgcn_mfma_f32_16x16x32_bf16(
                      cvt8(x0, x1), cvt8(vv[2 * s], vv[2 * s + 1]), acc, 0, 0, 0);
        }
    };

    stage(0, 0);
    for (int c = 0; c < NCHK; ++c) {
        vload(c);                           // 16 reg loads (V, L2)
        if (c + 1 < NCHK) {
            stage(c + 1, (c + 1) & 1);      // 8 gl_lds after V loads
            // queue: X(c)[landed] V(c)16 X(c+1)8 -> vmcnt(8): X(c),V(c) done,
            // X(c+1) stays in flight across the barrier.
            asm volatile("s_waitcnt vmcnt(8)" ::: "memory");
        } else {
            asm volatile("s_waitcnt vmcnt(0)" ::: "memory");
        }
        __builtin_amdgcn_s_barrier();
        __builtin_amdgcn_sched_barrier(0);
        compute(c & 1);
        __builtin_amdgcn_s_barrier();       // readers done before buf re-staged
    }

    // D: token = tt*16 + kg*4 + j, rank = rh*16 + r. Direct global store.
    const float sr = S[rh * 16 + r];
    float* Hq = Hpart + ((size_t)blockIdx.y * 8192 + t0 + tt * 16) * RANK;
    #pragma unroll
    for (int j = 0; j < 4; ++j)
        Hq[(size_t)(kg * 4 + j) * RANK + rh * 16 + r] = acc[j] * sr;
}

// ---------------- Kernel 1.5: H = sum_k Hpart[k] ----------------
template <int NKS>
__global__ __launch_bounds__(256)
void lora_hred(const float* __restrict__ Hpart, float* __restrict__ H)
{
    const int idx = blockIdx.x * 256 + threadIdx.x;       // float4 idx, 65536 total
    const float4* hp = reinterpret_cast<const float4*>(Hpart);
    float4 v = hp[idx];
    #pragma unroll
    for (int k = 1; k < NKS; ++k) {
        float4 p = hp[(size_t)k * 65536 + idx];
        v.x += p.x; v.y += p.y; v.z += p.z; v.w += p.w;
    }
    reinterpret_cast<float4*>(H)[idx] = v;
}

// ---------------- Kernel 2: Out = H @ U^T ----------------
// grid 1024, 256 thr (4 waves). Block: 32 tokens x 1024 cols -> each output
// row written in 1 KB contiguous bursts per wave (4 KB per block-row).
// H tile 4 KB -> LDS; U from L2 in 64-col groups.
__global__ __launch_bounds__(256, 4)
void lora_out(const float* __restrict__ H, const float* __restrict__ U,
              float* __restrict__ Out)
{
    __shared__ float Hs[32][33];

    const int tid  = threadIdx.x;
    const int wave = tid >> 6;
    const int lane = tid & 63;
    const int r    = lane & 15;
    const int kg   = lane >> 4;

    const int tt = blockIdx.x >> 2;
    const int cq = blockIdx.x & 3;
    const int t0 = tt * 32;

    // H tile 32x32 -> LDS (256 float4, one per thread)
    {
        float4 v = reinterpret_cast<const float4*>(H + (size_t)t0 * RANK)[tid];
        const int tok = tid >> 3;
        const int rr  = (tid & 7) * 4;
        Hs[tok][rr] = v.x; Hs[tok][rr + 1] = v.y;
        Hs[tok][rr + 2] = v.z; Hs[tok][rr + 3] = v.w;
    }
    __syncthreads();

    // B-frags: token = lane&15, k(rank) = kg*8+j
    bf16x8 hb[2];
    #pragma unroll
    for (int a = 0; a < 2; ++a)
        #pragma unroll
        for (int j = 0; j < 8; ++j) hb[a][j] = (__bf16)Hs[a * 16 + r][kg * 8 + j];

    const int wc0 = cq * 1024 + wave * 256;   // this wave's 256-col range

    #pragma unroll
    for (int g = 0; g < 4; ++g) {             // 64-col groups
        float4 u0[4], u1[4];
        #pragma unroll
        for (int b = 0; b < 4; ++b) {
            const float4* up = reinterpret_cast<const float4*>(
                U + (size_t)(wc0 + g * 64 + b * 16 + r) * RANK + kg * 8);
            u0[b] = up[0];
            u1[b] = up[1];
        }
        #pragma unroll
        for (int b = 0; b < 4; ++b) {
            bf16x8 ub = cvt8(u0[b], u1[b]);
            #pragma unroll
            for (int a = 0; a < 2; ++a) {
                f32x4 d = {0.f, 0.f, 0.f, 0.f};
                // A = U (m = col), B = H (n = token); D: row = token (lane&15),
                // col = wc0 + g*64 + b*16 + kg*4 + j -> f32x4 store
                d = __builtin_amdgcn_mfma_f32_16x16x32_bf16(ub, hb[a], d, 0, 0, 0);
                *reinterpret_cast<float4*>(
                    Out + (size_t)(t0 + a * 16 + r) * OUT_F
                        + wc0 + g * 64 + b * 16 + kg * 4)
                    = *reinterpret_cast<float4*>(&d);
            }
        }
    }
}

extern "C" void kernel_launch(void* const* d_in, const int* in_sizes, int n_in,
                              void* d_out, int out_size, void* d_ws, size_t ws_size,
                              hipStream_t stream) {
    const float* X = (const float*)d_in[0];
    const float* U = (const float*)d_in[1];
    const float* S = (const float*)d_in[2];
    const float* V = (const float*)d_in[3];
    float* Out = (float*)d_out;

    float* H     = (float*)d_ws;                 // 1 MB reduced H
    float* Hpart = (float*)d_ws + 262144;        // 2 MB partials (KS=2)

    if (ws_size >= (size_t)3 * 1024 * 1024) {
        lora_h<2><<<dim3(256, 2), 256, 0, stream>>>(X, S, V, Hpart);
        lora_hred<2><<<256, 256, 0, stream>>>(Hpart, H);
        lora_out<<<1024, 256, 0, stream>>>(H, U, Out);
    } else {
        lora_h<1><<<dim3(256, 1), 256, 0, stream>>>(X, S, V, H);
        lora_out<<<1024, 256, 0, stream>>>(H, U, Out);
    }
}

// Round 13
// 66.967 us; speedup vs baseline: 1.3584x; 1.3584x over previous
//
#include <hip/hip_runtime.h>
#include <hip/hip_bf16.h>

typedef __bf16 bf16x8 __attribute__((ext_vector_type(8)));
typedef float  f32x4  __attribute__((ext_vector_type(4)));

#define IN_F   4096
#define OUT_F  4096
#define RANK   32

__device__ __forceinline__ bf16x8 cvt8(float4 a, float4 b) {
    bf16x8 r;
    r[0] = (__bf16)a.x; r[1] = (__bf16)a.y; r[2] = (__bf16)a.z; r[3] = (__bf16)a.w;
    r[4] = (__bf16)b.x; r[5] = (__bf16)b.y; r[6] = (__bf16)b.z; r[7] = (__bf16)b.w;
    return r;
}

__device__ __forceinline__ void gl_lds16(const float* g, void* l) {
    __builtin_amdgcn_global_load_lds(
        (const __attribute__((address_space(1))) char*)g,
        (__attribute__((address_space(3))) char*)l, 16, 0, 0);
}

// ---------------- Kernel 1 (R11 exact, proven ~34 µs): Hpart[ks] = (X @ V^T) * S ----
// grid (128, KS), 256 thr. Block: 64 tokens x (IN_F/KS) feats, 64-feat chunks,
// triple-buffered (72 KB, 2 blocks/CU), stage-before-wait, counted vmcnt.
// V staged ONCE per block to LDS (no per-wave duplication): 192 MB logical total.
template <int KS>
__global__ __launch_bounds__(256, 2)
void lora_h(const float* __restrict__ X, const float* __restrict__ S,
            const float* __restrict__ V, float* __restrict__ Hpart)
{
    constexpr int F    = IN_F / KS;
    constexpr int NCHK = F / 64;

    __shared__ float4 XB[3][4][2][2][64];  // [buf][tt][s][h][slot] 48 KB
    __shared__ float4 VB[3][2][2][2][64];  // [buf][rh][s][h][slot] 24 KB

    const int tid  = threadIdx.x;
    const int wave = tid >> 6;
    const int lane = tid & 63;
    const int r    = lane & 15;
    const int kg   = lane >> 4;

    const int t0    = blockIdx.x * 64;
    const int fbase = blockIdx.y * F;

    const float s_lo = S[r];
    const float s_hi = S[16 + r];

    auto stage = [&](int c, int nb) {
        const int fc = fbase + ((c + blockIdx.x) & (NCHK - 1)) * 64;
        #pragma unroll
        for (int t = 0; t < 6; ++t) {
            const int inst = wave * 6 + t;
            if (inst < 16) {            // X: tt, s, h
                const int tt = inst >> 2, s = (inst >> 1) & 1, h2 = inst & 1;
                gl_lds16(X + (size_t)(t0 + tt * 16 + r) * IN_F
                           + fc + s * 32 + h2 * 16 + kg * 4,
                         (void*)&XB[nb][tt][s][h2][0]);
            } else {                    // V: rh, s, h
                const int v = inst - 16;
                const int vr = v >> 2, s = (v >> 1) & 1, h2 = v & 1;
                gl_lds16(V + (size_t)(vr * 16 + r) * IN_F
                           + fc + s * 32 + h2 * 16 + kg * 4,
                         (void*)&VB[nb][vr][s][h2][0]);
            }
        }
    };

    const int h  = kg >> 1;
    const int qb = (kg & 1) * 2;

    f32x4 acc[2] = {};                  // rank halves for this wave's 16 tokens

    auto compute = [&](int cur) {
        #pragma unroll
        for (int s = 0; s < 2; ++s) {
            float4 x0 = *(const float4*)&XB[cur][wave][s][h][qb * 16 + r];
            float4 x1 = *(const float4*)&XB[cur][wave][s][h][(qb + 1) * 16 + r];
            bf16x8 xb = cvt8(x0, x1);
            #pragma unroll
            for (int rh = 0; rh < 2; ++rh) {
                float4 v0 = *(const float4*)&VB[cur][rh][s][h][qb * 16 + r];
                float4 v1 = *(const float4*)&VB[cur][rh][s][h][(qb + 1) * 16 + r];
                acc[rh] = __builtin_amdgcn_mfma_f32_16x16x32_bf16(
                              xb, cvt8(v0, v1), acc[rh], 0, 0, 0);
            }
        }
    };

    stage(0, 0);
    stage(1, 1);

    for (int c = 0; c < NCHK; ++c) {
        if (c + 2 < NCHK) {
            stage(c + 2, (c + 2) % 3);
            asm volatile("s_waitcnt vmcnt(12)" ::: "memory");
        } else if (c + 1 < NCHK) {
            asm volatile("s_waitcnt vmcnt(6)" ::: "memory");
        } else {
            asm volatile("s_waitcnt vmcnt(0)" ::: "memory");
        }
        __builtin_amdgcn_s_barrier();
        __builtin_amdgcn_sched_barrier(0);
        compute(c % 3);
        __builtin_amdgcn_s_barrier();
    }

    // D: token = wave*16 + kg*4 + j, rank = rh*16 + r
    float* Hq = Hpart + ((size_t)blockIdx.y * 8192 + t0) * RANK;
    #pragma unroll
    for (int j = 0; j < 4; ++j) {
        const int tok = wave * 16 + kg * 4 + j;
        Hq[(size_t)tok * RANK + r]      = acc[0][j] * s_lo;
        Hq[(size_t)tok * RANK + 16 + r] = acc[1][j] * s_hi;
    }
}

// ---------------- Kernel 1.5: H = sum_k Hpart[k] (4 MB -> 1 MB) ----------------
template <int NKS>
__global__ __launch_bounds__(256)
void lora_hred(const float* __restrict__ Hpart, float* __restrict__ H)
{
    const int idx = blockIdx.x * 256 + threadIdx.x;       // float4 idx, 65536 total
    const float4* hp = reinterpret_cast<const float4*>(Hpart);
    float4 v = hp[idx];
    #pragma unroll
    for (int k = 1; k < NKS; ++k) {
        float4 p = hp[(size_t)k * 65536 + idx];
        v.x += p.x; v.y += p.y; v.z += p.z; v.w += p.w;
    }
    reinterpret_cast<float4*>(H)[idx] = v;
}

// ---------------- Kernel 2 (R12 exact, proven ~8-9 µs): Out = H @ U^T ----------------
// grid 1024, 256 thr. Block: 32 tokens x 1024 cols; sequential U stream,
// 1 KB contiguous write bursts per row per wave.
__global__ __launch_bounds__(256, 4)
void lora_out(const float* __restrict__ H, const float* __restrict__ U,
              float* __restrict__ Out)
{
    __shared__ float Hs[32][33];

    const int tid  = threadIdx.x;
    const int wave = tid >> 6;
    const int lane = tid & 63;
    const int r    = lane & 15;
    const int kg   = lane >> 4;

    const int tt = blockIdx.x >> 2;
    const int cq = blockIdx.x & 3;
    const int t0 = tt * 32;

    {
        float4 v = reinterpret_cast<const float4*>(H + (size_t)t0 * RANK)[tid];
        const int tok = tid >> 3;
        const int rr  = (tid & 7) * 4;
        Hs[tok][rr] = v.x; Hs[tok][rr + 1] = v.y;
        Hs[tok][rr + 2] = v.z; Hs[tok][rr + 3] = v.w;
    }
    __syncthreads();

    bf16x8 hb[2];
    #pragma unroll
    for (int a = 0; a < 2; ++a)
        #pragma unroll
        for (int j = 0; j < 8; ++j) hb[a][j] = (__bf16)Hs[a * 16 + r][kg * 8 + j];

    const int wc0 = cq * 1024 + wave * 256;

    #pragma unroll
    for (int g = 0; g < 4; ++g) {
        float4 u0[4], u1[4];
        #pragma unroll
        for (int b = 0; b < 4; ++b) {
            const float4* up = reinterpret_cast<const float4*>(
                U + (size_t)(wc0 + g * 64 + b * 16 + r) * RANK + kg * 8);
            u0[b] = up[0];
            u1[b] = up[1];
        }
        #pragma unroll
        for (int b = 0; b < 4; ++b) {
            bf16x8 ub = cvt8(u0[b], u1[b]);
            #pragma unroll
            for (int a = 0; a < 2; ++a) {
                f32x4 d = {0.f, 0.f, 0.f, 0.f};
                d = __builtin_amdgcn_mfma_f32_16x16x32_bf16(ub, hb[a], d, 0, 0, 0);
                *reinterpret_cast<float4*>(
                    Out + (size_t)(t0 + a * 16 + r) * OUT_F
                        + wc0 + g * 64 + b * 16 + kg * 4)
                    = *reinterpret_cast<float4*>(&d);
            }
        }
    }
}

extern "C" void kernel_launch(void* const* d_in, const int* in_sizes, int n_in,
                              void* d_out, int out_size, void* d_ws, size_t ws_size,
                              hipStream_t stream) {
    const float* X = (const float*)d_in[0];
    const float* U = (const float*)d_in[1];
    const float* S = (const float*)d_in[2];
    const float* V = (const float*)d_in[3];
    float* Out = (float*)d_out;

    float* H     = (float*)d_ws;                 // 1 MB reduced H
    float* Hpart = (float*)d_ws + 262144;        // 4 MB partials (KS=4)

    if (ws_size >= (size_t)5 * 1024 * 1024) {
        lora_h<4><<<dim3(128, 4), 256, 0, stream>>>(X, S, V, Hpart);
        lora_hred<4><<<256, 256, 0, stream>>>(Hpart, H);
        lora_out<<<1024, 256, 0, stream>>>(H, U, Out);
    } else {
        lora_h<1><<<dim3(128, 1), 256, 0, stream>>>(X, S, V, H);
        lora_out<<<1024, 256, 0, stream>>>(H, U, Out);
    }
}